// Round 10
// baseline (267.716 us; speedup 1.0000x reference)
//
#include <hip/hip_runtime.h>

// LNSNet forward, R9: THREE kernels.
//  k1: conv1 sliding half-row packed fp32 + weight prep + done[] zeroing
//  k2: conv2 bf16 MFMA, 3 blocks/image, channels-last; pooling scratch stride
//      24->26 ushorts (13 dwords, odd) -> bank-conflict-free (R8 measured
//      790K conflict-cycles/rep from the old 12-dword stride = 8 banks)
//  k3: fc1 bf16 MFMA split-K with SPIN-FREE ticket epilogue: 16mt x 32ks
//      blocks; last arriver per mt reduces + bias + relu + fc2. No k4.
// R6 lesson refined: cross-XCD SPINNING melts down; a single release-fence +
// atomicAdd ticket per block (512 total, no polling) is the bounded-risk form.

#define B 512
#define POS 676
#define ICP 36
#define P2SZ (64*12*12)
#define SCR 26             // pooling scratch stride (ushorts): 13 dwords, odd -> conflict-free

typedef unsigned short ushort_t;
typedef ushort_t ushort4v __attribute__((ext_vector_type(4)));
typedef short s16x8 __attribute__((ext_vector_type(8)));
typedef float f32x4 __attribute__((ext_vector_type(4)));
typedef float f32x2 __attribute__((ext_vector_type(2)));

__device__ __forceinline__ ushort_t f2bf(float f) {
    union { float f; unsigned u; } a; a.f = f;
    unsigned r = a.u + 0x7FFFu + ((a.u >> 16) & 1u);
    return (ushort_t)(r >> 16);
}
__device__ __forceinline__ float bf2f(ushort_t u) {
    union { unsigned u; float f; } a; a.u = ((unsigned)u) << 16;
    return a.f;
}

#define N_WR (64 * 9 * 32)
#define N_WF (128 * 9216)
#define CONV1_BLOCKS 3328
#define PREP_BLOCKS  4680

// ---------------- k1: conv1 sliding half-row + weight prep + done zero ----------------
__global__ __launch_bounds__(256) void conv1_prep(const float* __restrict__ x,
                                                  const float* __restrict__ w,
                                                  const float* __restrict__ bias,
                                                  const float* __restrict__ c2w,
                                                  const float* __restrict__ f1w,
                                                  ushort_t* __restrict__ out,
                                                  ushort_t* __restrict__ wr,
                                                  ushort_t* __restrict__ wfb,
                                                  unsigned* __restrict__ done) {
    int blk = blockIdx.x;
    if (blk >= CONV1_BLOCKS) {
        if (blk == CONV1_BLOCKS && threadIdx.x < 16) done[threadIdx.x] = 0u;
        int t = (blk - CONV1_BLOCKS) * 256 + threadIdx.x;
        if (t < N_WR) {
            int ic  = t & 31;
            int tap = (t >> 5) % 9;
            int oc  = t / 288;
            wr[t] = f2bf(c2w[oc * 288 + ic * 9 + tap]);
        } else if (t < N_WR + N_WF) {
            // fc1 weights permuted: out k' = pos*64 + oc  <-  in k = oc*144 + pos
            int i  = t - N_WR;
            int oc  = i & 63;
            int pos = (i >> 6) % 144;
            int n   = i / 9216;
            wfb[i] = f2bf(f1w[(size_t)n * 9216 + oc * 144 + pos]);
        }
        return;
    }
    int t = blk * 256 + threadIdx.x;
    int ic = t & 31;
    int r  = t >> 5;
    int h  = r & 1;
    int r2 = r >> 1;
    int py = r2 % 26;
    int b  = r2 / 26;
    int px0 = h * 13;

    const float* wp = w + ic * 9;
    float w00 = wp[0], w01 = wp[1], w02 = wp[2];
    float w10 = wp[3], w11 = wp[4], w12 = wp[5];
    float w20 = wp[6], w21 = wp[7], w22 = wp[8];
    float bv = bias[ic];

    const float* xr = x + b * (54 * 54) + (2 * py) * 54 + 2 * px0;
    ushort_t* po = out + ((size_t)b * POS + py * 26 + px0) * 32 + ic;

    f32x2 p[4], q[4];
#pragma unroll
    for (int rr = 0; rr < 4; ++rr) p[rr] = *reinterpret_cast<const f32x2*>(xr + rr * 54);
#pragma unroll
    for (int rr = 0; rr < 4; ++rr) q[rr] = *reinterpret_cast<const f32x2*>(xr + rr * 54 + 2);

#pragma unroll
    for (int j = 0; j < 13; ++j) {
        f32x2 mid[4];
#pragma unroll
        for (int rr = 0; rr < 4; ++rr) mid[rr] = (f32x2){p[rr].y, q[rr].x};

        f32x2 s0 = p[0] * (f32x2)w00 + mid[0] * (f32x2)w01 + q[0] * (f32x2)w02
                 + p[1] * (f32x2)w10 + mid[1] * (f32x2)w11 + q[1] * (f32x2)w12
                 + p[2] * (f32x2)w20 + mid[2] * (f32x2)w21 + q[2] * (f32x2)w22;
        f32x2 s1 = p[1] * (f32x2)w00 + mid[1] * (f32x2)w01 + q[1] * (f32x2)w02
                 + p[2] * (f32x2)w10 + mid[2] * (f32x2)w11 + q[2] * (f32x2)w12
                 + p[3] * (f32x2)w20 + mid[3] * (f32x2)w21 + q[3] * (f32x2)w22;

        float m = fmaxf(fmaxf(s0.x, s0.y), fmaxf(s1.x, s1.y));
        po[j * 32] = f2bf(fmaxf(m + bv, 0.0f));
        if (j < 12) {
#pragma unroll
            for (int rr = 0; rr < 4; ++rr) {
                p[rr] = q[rr];
                q[rr] = *reinterpret_cast<const f32x2*>(xr + rr * 54 + 2 * j + 4);
            }
        }
    }
}

// ---------------- k2: conv2 MFMA, conflict-free scratch, channels-last out ----------------
__global__ __launch_bounds__(256) void conv2_mfma(const ushort_t* __restrict__ p1,
                                                  const ushort_t* __restrict__ wr,
                                                  const float* __restrict__ bias,
                                                  ushort_t* __restrict__ pool2cl) {
    __shared__ ushort_t lds[260 * ICP];   // 18,720 B
    int blk = blockIdx.x;
    int b = blk / 3, c = blk % 3;
    int tid = threadIdx.x;

    const ushort_t* src = p1 + ((size_t)b * POS + 8 * c * 26) * 32;
    for (int t = tid; t < 260 * 8; t += 256) {
        int pos = t >> 3, off = (t & 7) * 4;
        ushort4v v = *reinterpret_cast<const ushort4v*>(src + pos * 32 + off);
        *reinterpret_cast<ushort4v*>(&lds[pos * ICP + off]) = v;
    }
    __syncthreads();

    int lane = tid & 63, wid = tid >> 6;
    int quad = lane >> 4, lr = lane & 15;

    int ebase[3];
#pragma unroll
    for (int t = 0; t < 3; ++t) {
        int m  = t * 16 + lr;
        int yl = m / 24;
        int xx = m - yl * 24;
        ebase[t] = ((2 * wid + yl) * 26 + xx) * ICP + quad * 8;
    }

    f32x4 acc[3][4];
#pragma unroll
    for (int t = 0; t < 3; ++t)
#pragma unroll
        for (int n = 0; n < 4; ++n) acc[t][n] = (f32x4){0.f, 0.f, 0.f, 0.f};

    const ushort_t* wb = wr + (size_t)lr * 288 + quad * 8;

#pragma unroll
    for (int tap = 0; tap < 9; ++tap) {
        int ky = tap / 3, kx = tap % 3;
        int koff = (ky * 26 + kx) * ICP;
        s16x8 a[3];
#pragma unroll
        for (int t = 0; t < 3; ++t) {
            union { ushort4v s[2]; s16x8 v; } u;
            u.s[0] = *reinterpret_cast<const ushort4v*>(&lds[ebase[t] + koff]);
            u.s[1] = *reinterpret_cast<const ushort4v*>(&lds[ebase[t] + koff + 4]);
            a[t] = u.v;
        }
        s16x8 bf[4];
#pragma unroll
        for (int n = 0; n < 4; ++n)
            bf[n] = *reinterpret_cast<const s16x8*>(wb + n * 4608 + tap * 32);
#pragma unroll
        for (int t = 0; t < 3; ++t)
#pragma unroll
            for (int n = 0; n < 4; ++n)
                acc[t][n] = __builtin_amdgcn_mfma_f32_16x16x32_bf16(a[t], bf[n], acc[t][n], 0, 0, 0);
    }
    __syncthreads();

    // x-pool -> per-wave scratch, stride SCR=26 ushorts (conflict-free)
    ushort_t* scr = lds + wid * (64 * SCR);
#pragma unroll
    for (int t = 0; t < 3; ++t)
#pragma unroll
        for (int n = 0; n < 4; ++n) {
            int oc = n * 16 + lr;
            int i0 = t * 8 + quad * 2;
            float v0 = fmaxf(acc[t][n][0], acc[t][n][1]);
            float v1 = fmaxf(acc[t][n][2], acc[t][n][3]);
            union { ushort_t u2[2]; unsigned w; } pk;
            pk.u2[0] = f2bf(v0); pk.u2[1] = f2bf(v1);
            *reinterpret_cast<unsigned*>(&scr[oc * SCR + i0]) = pk.w;
        }
    int oc = lane;
    const ushort_t* row = scr + oc * SCR;
    float bv = bias[oc];
    int py = c * 4 + wid;
    ushort_t* po = pool2cl + ((size_t)b * 144 + py * 12) * 64 + oc;
#pragma unroll
    for (int px = 0; px < 12; ++px) {
        float r0 = bf2f(row[px]);
        float r1 = bf2f(row[px + 12]);
        po[px * 64] = f2bf(fmaxf(fmaxf(r0, r1) + bv, 0.0f));
    }
}

// ---------------- k3: fc1 MFMA split-K + ticket epilogue (reduce+relu+fc2) ----------------
// grid = 512 blocks: mt = blk>>5 (32 m-rows), ks = blk&31 (K-chunk 288).
// Block: 4 waves, wave wid covers n0 = wid*32 (2 n-tiles), 2 m-tiles -> 4 MFMA/kstep.
// Last arriver per mt (atomicAdd ticket, NO spinning) reduces 32 slabs + fc2.
__global__ __launch_bounds__(256) void fc1fc2_fused(const ushort_t* __restrict__ A,
                                                    const ushort_t* __restrict__ W,
                                                    const float* __restrict__ b1,
                                                    const float* __restrict__ w2,
                                                    const float* __restrict__ b2,
                                                    float* __restrict__ Cpart,
                                                    float* __restrict__ out,
                                                    unsigned* __restrict__ done) {
    int blk = blockIdx.x;
    int mt = blk >> 5;
    int ks = blk & 31;
    int tid = threadIdx.x;
    int lane = tid & 63, wid = tid >> 6;
    int lr = lane & 15, quad = lane >> 4;

    int m0 = mt * 32;
    int n0 = wid * 32;
    int k0 = ks * 288 + quad * 8;
    const ushort_t* a0 = A + (size_t)(m0 + lr) * 9216 + k0;
    const ushort_t* a1 = a0 + (size_t)16 * 9216;
    const ushort_t* bp0 = W + (size_t)(n0 + lr) * 9216 + k0;
    const ushort_t* bp1 = bp0 + (size_t)16 * 9216;

    f32x4 acc[2][2];
#pragma unroll
    for (int i = 0; i < 2; ++i)
#pragma unroll
        for (int j = 0; j < 2; ++j) acc[i][j] = (f32x4){0.f, 0.f, 0.f, 0.f};

#pragma unroll
    for (int kk = 0; kk < 9; ++kk) {
        s16x8 av0 = *reinterpret_cast<const s16x8*>(a0 + kk * 32);
        s16x8 av1 = *reinterpret_cast<const s16x8*>(a1 + kk * 32);
        s16x8 bv0 = *reinterpret_cast<const s16x8*>(bp0 + kk * 32);
        s16x8 bv1 = *reinterpret_cast<const s16x8*>(bp1 + kk * 32);
        acc[0][0] = __builtin_amdgcn_mfma_f32_16x16x32_bf16(av0, bv0, acc[0][0], 0, 0, 0);
        acc[0][1] = __builtin_amdgcn_mfma_f32_16x16x32_bf16(av0, bv1, acc[0][1], 0, 0, 0);
        acc[1][0] = __builtin_amdgcn_mfma_f32_16x16x32_bf16(av1, bv0, acc[1][0], 0, 0, 0);
        acc[1][1] = __builtin_amdgcn_mfma_f32_16x16x32_bf16(av1, bv1, acc[1][1], 0, 0, 0);
    }

    float* cp = Cpart + (size_t)ks * (512 * 128);
#pragma unroll
    for (int i = 0; i < 2; ++i) {
        int crow = m0 + i * 16 + quad * 4;
#pragma unroll
        for (int j = 0; j < 2; ++j) {
            int col = n0 + j * 16 + lr;
#pragma unroll
            for (int r = 0; r < 4; ++r)
                cp[(size_t)(crow + r) * 128 + col] = acc[i][j][r];
        }
    }

    // ---- ticket: release slab, count arrival; last of 32 does the epilogue ----
    __threadfence();                 // release Cpart writes device-wide
    __syncthreads();                 // all threads' stores precede the ticket
    __shared__ unsigned is_last;
    if (tid == 0)
        is_last = (atomicAdd(&done[mt], 1u) == 31u) ? 1u : 0u;
    __syncthreads();
    if (!is_last) return;            // no spinning: 31 blocks exit
    __threadfence();                 // acquire other blocks' slabs

    __shared__ float h[32][128];     // 16 KB
    for (int idx = tid; idx < 32 * 128; idx += 256) {
        int mm = idx >> 7, nn = idx & 127;
        float s = 0.f;
#pragma unroll
        for (int k2 = 0; k2 < 32; ++k2)
            s += Cpart[(size_t)k2 * (512 * 128) + (size_t)(m0 + mm) * 128 + nn];
        h[mm][nn] = fmaxf(s + b1[nn], 0.0f);
    }
    __syncthreads();
    for (int idx = tid; idx < 32 * 10; idx += 256) {
        int mm = idx / 10, o = idx % 10;
        const float* wp = w2 + o * 128;
        float a2 = 0.f;
#pragma unroll 8
        for (int j = 0; j < 128; ++j) a2 += h[mm][j] * wp[j];
        out[(m0 + mm) * 10 + o] = a2 + b2[o];
    }
}

extern "C" void kernel_launch(void* const* d_in, const int* in_sizes, int n_in,
                              void* d_out, int out_size, void* d_ws, size_t ws_size,
                              hipStream_t stream) {
    const float* x       = (const float*)d_in[0];
    const float* conv1_w = (const float*)d_in[1];
    const float* conv1_b = (const float*)d_in[2];
    const float* conv2_w = (const float*)d_in[3];
    const float* conv2_b = (const float*)d_in[4];
    const float* fc1_w   = (const float*)d_in[5];
    const float* fc1_b   = (const float*)d_in[6];
    const float* fc2_w   = (const float*)d_in[7];
    const float* fc2_b   = (const float*)d_in[8];
    float* out = (float*)d_out;

    char* ws = (char*)d_ws;
    ushort_t* pool1 = (ushort_t*)ws;
    ws += (size_t)B * POS * 32 * sizeof(ushort_t);
    ushort_t* wr = (ushort_t*)ws;
    ws += N_WR * sizeof(ushort_t) + 128;
    ushort_t* wfb = (ushort_t*)ws;
    ws += N_WF * sizeof(ushort_t) + 128;
    ushort_t* pool2cl = (ushort_t*)ws;
    ws += (size_t)B * P2SZ * sizeof(ushort_t) + 128;
    float* Cpart = (float*)ws;
    ws += (size_t)32 * 512 * 128 * sizeof(float) + 128;
    unsigned* done = (unsigned*)ws;          // 16 x u32, zeroed by k1
    ws += 256;

    conv1_prep<<<CONV1_BLOCKS + PREP_BLOCKS, 256, 0, stream>>>(
        x, conv1_w, conv1_b, conv2_w, fc1_w, pool1, wr, wfb, done);
    conv2_mfma<<<B * 3, 256, 0, stream>>>(pool1, wr, conv2_b, pool2cl);
    fc1fc2_fused<<<512, 256, 0, stream>>>(pool2cl, wfb, fc1_b, fc2_w, fc2_b,
                                          Cpart, out, done);
}

// Round 11
// 179.813 us; speedup vs baseline: 1.4889x; 1.4889x over previous
//
#include <hip/hip_runtime.h>

// LNSNet forward, R10: revert R9's fence experiment (512 device-scope fences
// cost ~0.3us each, serialized -> +136us). R7 4-kernel skeleton + two fixes:
//  k2: SCR=26 pooling scratch (odd dword stride, conflict-free; R8 measured
//      790K conflict-cycles/rep at stride 12) and __launch_bounds__(256,6)
//      (VGPR<=85 -> 6 blocks/CU -> all 1536 blocks co-resident; R8 showed
//      occupancy 20% = 5-blocks/CU residency + straggler tail at VGPR=92).
// NEVER use device-scope fences in-kernel on MI355X (R6+R9 evidence).

#define B 512
#define POS 676
#define ICP 36
#define P2SZ (64*12*12)
#define SCR 26             // ushort stride = 13 dwords, odd -> all 32 banks hit

typedef unsigned short ushort_t;
typedef ushort_t ushort4v __attribute__((ext_vector_type(4)));
typedef short s16x8 __attribute__((ext_vector_type(8)));
typedef float f32x4 __attribute__((ext_vector_type(4)));
typedef float f32x2 __attribute__((ext_vector_type(2)));

__device__ __forceinline__ ushort_t f2bf(float f) {
    union { float f; unsigned u; } a; a.f = f;
    unsigned r = a.u + 0x7FFFu + ((a.u >> 16) & 1u);
    return (ushort_t)(r >> 16);
}
__device__ __forceinline__ float bf2f(ushort_t u) {
    union { unsigned u; float f; } a; a.u = ((unsigned)u) << 16;
    return a.f;
}

#define N_WR (64 * 9 * 32)
#define N_WF (128 * 9216)
#define CONV1_BLOCKS 3328
#define PREP_BLOCKS  4680

// ---------------- k1: conv1 sliding half-row (packed fp32) + weight prep ----------------
__global__ __launch_bounds__(256) void conv1_prep(const float* __restrict__ x,
                                                  const float* __restrict__ w,
                                                  const float* __restrict__ bias,
                                                  const float* __restrict__ c2w,
                                                  const float* __restrict__ f1w,
                                                  ushort_t* __restrict__ out,
                                                  ushort_t* __restrict__ wr,
                                                  ushort_t* __restrict__ wfb) {
    int blk = blockIdx.x;
    if (blk >= CONV1_BLOCKS) {
        int t = (blk - CONV1_BLOCKS) * 256 + threadIdx.x;
        if (t < N_WR) {
            int ic  = t & 31;
            int tap = (t >> 5) % 9;
            int oc  = t / 288;
            wr[t] = f2bf(c2w[oc * 288 + ic * 9 + tap]);
        } else if (t < N_WR + N_WF) {
            // fc1 weights permuted: out k' = pos*64 + oc  <-  in k = oc*144 + pos
            int i  = t - N_WR;
            int oc  = i & 63;
            int pos = (i >> 6) % 144;
            int n   = i / 9216;
            wfb[i] = f2bf(f1w[(size_t)n * 9216 + oc * 144 + pos]);
        }
        return;
    }
    int t = blk * 256 + threadIdx.x;
    int ic = t & 31;
    int r  = t >> 5;
    int h  = r & 1;
    int r2 = r >> 1;
    int py = r2 % 26;
    int b  = r2 / 26;
    int px0 = h * 13;

    const float* wp = w + ic * 9;
    float w00 = wp[0], w01 = wp[1], w02 = wp[2];
    float w10 = wp[3], w11 = wp[4], w12 = wp[5];
    float w20 = wp[6], w21 = wp[7], w22 = wp[8];
    float bv = bias[ic];

    const float* xr = x + b * (54 * 54) + (2 * py) * 54 + 2 * px0;
    ushort_t* po = out + ((size_t)b * POS + py * 26 + px0) * 32 + ic;

    f32x2 p[4], q[4];
#pragma unroll
    for (int rr = 0; rr < 4; ++rr) p[rr] = *reinterpret_cast<const f32x2*>(xr + rr * 54);
#pragma unroll
    for (int rr = 0; rr < 4; ++rr) q[rr] = *reinterpret_cast<const f32x2*>(xr + rr * 54 + 2);

#pragma unroll
    for (int j = 0; j < 13; ++j) {
        f32x2 mid[4];
#pragma unroll
        for (int rr = 0; rr < 4; ++rr) mid[rr] = (f32x2){p[rr].y, q[rr].x};

        f32x2 s0 = p[0] * (f32x2)w00 + mid[0] * (f32x2)w01 + q[0] * (f32x2)w02
                 + p[1] * (f32x2)w10 + mid[1] * (f32x2)w11 + q[1] * (f32x2)w12
                 + p[2] * (f32x2)w20 + mid[2] * (f32x2)w21 + q[2] * (f32x2)w22;
        f32x2 s1 = p[1] * (f32x2)w00 + mid[1] * (f32x2)w01 + q[1] * (f32x2)w02
                 + p[2] * (f32x2)w10 + mid[2] * (f32x2)w11 + q[2] * (f32x2)w12
                 + p[3] * (f32x2)w20 + mid[3] * (f32x2)w21 + q[3] * (f32x2)w22;

        float m = fmaxf(fmaxf(s0.x, s0.y), fmaxf(s1.x, s1.y));
        po[j * 32] = f2bf(fmaxf(m + bv, 0.0f));
        if (j < 12) {
#pragma unroll
            for (int rr = 0; rr < 4; ++rr) {
                p[rr] = q[rr];
                q[rr] = *reinterpret_cast<const f32x2*>(xr + rr * 54 + 2 * j + 4);
            }
        }
    }
}

// ---------------- k2: conv2 MFMA, 6 blocks/CU, conflict-free scratch ----------------
__global__ __launch_bounds__(256, 6) void conv2_mfma(const ushort_t* __restrict__ p1,
                                                     const ushort_t* __restrict__ wr,
                                                     const float* __restrict__ bias,
                                                     ushort_t* __restrict__ pool2cl) {
    __shared__ ushort_t lds[260 * ICP];   // 18,720 B
    int blk = blockIdx.x;
    int b = blk / 3, c = blk % 3;
    int tid = threadIdx.x;

    const ushort_t* src = p1 + ((size_t)b * POS + 8 * c * 26) * 32;
    for (int t = tid; t < 260 * 8; t += 256) {
        int pos = t >> 3, off = (t & 7) * 4;
        ushort4v v = *reinterpret_cast<const ushort4v*>(src + pos * 32 + off);
        *reinterpret_cast<ushort4v*>(&lds[pos * ICP + off]) = v;
    }
    __syncthreads();

    int lane = tid & 63, wid = tid >> 6;
    int quad = lane >> 4, lr = lane & 15;

    int ebase[3];
#pragma unroll
    for (int t = 0; t < 3; ++t) {
        int m  = t * 16 + lr;
        int yl = m / 24;
        int xx = m - yl * 24;
        ebase[t] = ((2 * wid + yl) * 26 + xx) * ICP + quad * 8;
    }

    f32x4 acc[3][4];
#pragma unroll
    for (int t = 0; t < 3; ++t)
#pragma unroll
        for (int n = 0; n < 4; ++n) acc[t][n] = (f32x4){0.f, 0.f, 0.f, 0.f};

    const ushort_t* wb = wr + (size_t)lr * 288 + quad * 8;

#pragma unroll
    for (int tap = 0; tap < 9; ++tap) {
        int ky = tap / 3, kx = tap % 3;
        int koff = (ky * 26 + kx) * ICP;
        s16x8 a[3];
#pragma unroll
        for (int t = 0; t < 3; ++t) {
            union { ushort4v s[2]; s16x8 v; } u;
            u.s[0] = *reinterpret_cast<const ushort4v*>(&lds[ebase[t] + koff]);
            u.s[1] = *reinterpret_cast<const ushort4v*>(&lds[ebase[t] + koff + 4]);
            a[t] = u.v;
        }
        s16x8 bf[4];
#pragma unroll
        for (int n = 0; n < 4; ++n)
            bf[n] = *reinterpret_cast<const s16x8*>(wb + n * 4608 + tap * 32);
#pragma unroll
        for (int t = 0; t < 3; ++t)
#pragma unroll
            for (int n = 0; n < 4; ++n)
                acc[t][n] = __builtin_amdgcn_mfma_f32_16x16x32_bf16(a[t], bf[n], acc[t][n], 0, 0, 0);
    }
    __syncthreads();

    // x-pool -> per-wave scratch, stride SCR=26 (conflict-free)
    ushort_t* scr = lds + wid * (64 * SCR);
#pragma unroll
    for (int t = 0; t < 3; ++t)
#pragma unroll
        for (int n = 0; n < 4; ++n) {
            int oc = n * 16 + lr;
            int i0 = t * 8 + quad * 2;
            float v0 = fmaxf(acc[t][n][0], acc[t][n][1]);
            float v1 = fmaxf(acc[t][n][2], acc[t][n][3]);
            union { ushort_t u2[2]; unsigned w; } pk;
            pk.u2[0] = f2bf(v0); pk.u2[1] = f2bf(v1);
            *reinterpret_cast<unsigned*>(&scr[oc * SCR + i0]) = pk.w;
        }
    int oc = lane;
    const ushort_t* row = scr + oc * SCR;
    float bv = bias[oc];
    int py = c * 4 + wid;
    ushort_t* po = pool2cl + ((size_t)b * 144 + py * 12) * 64 + oc;
#pragma unroll
    for (int px = 0; px < 12; ++px) {
        float r0 = bf2f(row[px]);
        float r1 = bf2f(row[px + 12]);
        po[px * 64] = f2bf(fmaxf(fmaxf(r0, r1) + bv, 0.0f));
    }
}

// ---------------- k3: fc1 bf16 MFMA, 32x32-tile waves, permuted K ----------------
__global__ __launch_bounds__(256) void fc1_mfma(const ushort_t* __restrict__ A,
                                                 const ushort_t* __restrict__ W,
                                                 float* __restrict__ Cpart) {
    int tid = threadIdx.x;
    int lane = tid & 63, wid = tid >> 6;
    int lr = lane & 15, quad = lane >> 4;
    int w  = blockIdx.x * 4 + wid;
    int nt = w & 3;
    int ks = (w >> 2) & 31;
    int mt = w >> 7;

    int m0 = mt * 32;
    int n0 = nt * 32;
    int k0 = ks * 288 + quad * 8;
    const ushort_t* a0 = A + (size_t)(m0 + lr) * 9216 + k0;
    const ushort_t* a1 = a0 + (size_t)16 * 9216;
    const ushort_t* b0 = W + (size_t)(n0 + lr) * 9216 + k0;
    const ushort_t* b1 = b0 + (size_t)16 * 9216;

    f32x4 acc[2][2];
#pragma unroll
    for (int i = 0; i < 2; ++i)
#pragma unroll
        for (int j = 0; j < 2; ++j) acc[i][j] = (f32x4){0.f, 0.f, 0.f, 0.f};

#pragma unroll
    for (int kk = 0; kk < 9; ++kk) {
        s16x8 av0 = *reinterpret_cast<const s16x8*>(a0 + kk * 32);
        s16x8 av1 = *reinterpret_cast<const s16x8*>(a1 + kk * 32);
        s16x8 bv0 = *reinterpret_cast<const s16x8*>(b0 + kk * 32);
        s16x8 bv1 = *reinterpret_cast<const s16x8*>(b1 + kk * 32);
        acc[0][0] = __builtin_amdgcn_mfma_f32_16x16x32_bf16(av0, bv0, acc[0][0], 0, 0, 0);
        acc[0][1] = __builtin_amdgcn_mfma_f32_16x16x32_bf16(av0, bv1, acc[0][1], 0, 0, 0);
        acc[1][0] = __builtin_amdgcn_mfma_f32_16x16x32_bf16(av1, bv0, acc[1][0], 0, 0, 0);
        acc[1][1] = __builtin_amdgcn_mfma_f32_16x16x32_bf16(av1, bv1, acc[1][1], 0, 0, 0);
    }

    float* cp = Cpart + (size_t)ks * (512 * 128);
#pragma unroll
    for (int i = 0; i < 2; ++i) {
        int crow = m0 + i * 16 + quad * 4;
#pragma unroll
        for (int j = 0; j < 2; ++j) {
            int col = n0 + j * 16 + lr;
#pragma unroll
            for (int r = 0; r < 4; ++r)
                cp[(size_t)(crow + r) * 128 + col] = acc[i][j][r];
        }
    }
}

// ---------------- k4: fc1 reduce + bias + relu + fc2 ----------------
__global__ __launch_bounds__(128) void fc1fc2(const float* __restrict__ Cpart,
                                              const float* __restrict__ b1,
                                              const float* __restrict__ w2,
                                              const float* __restrict__ b2,
                                              float* __restrict__ out) {
    __shared__ float h[128];
    int b = blockIdx.x, k = threadIdx.x;
    float s = 0.f;
#pragma unroll
    for (int ks = 0; ks < 32; ++ks) s += Cpart[(size_t)ks * (512 * 128) + b * 128 + k];
    h[k] = fmaxf(s + b1[k], 0.0f);
    __syncthreads();
    if (k < 10) {
        const float* wp = w2 + k * 128;
        float acc = 0.f;
#pragma unroll 8
        for (int j = 0; j < 128; ++j) acc += h[j] * wp[j];
        out[b * 10 + k] = acc + b2[k];
    }
}

extern "C" void kernel_launch(void* const* d_in, const int* in_sizes, int n_in,
                              void* d_out, int out_size, void* d_ws, size_t ws_size,
                              hipStream_t stream) {
    const float* x       = (const float*)d_in[0];
    const float* conv1_w = (const float*)d_in[1];
    const float* conv1_b = (const float*)d_in[2];
    const float* conv2_w = (const float*)d_in[3];
    const float* conv2_b = (const float*)d_in[4];
    const float* fc1_w   = (const float*)d_in[5];
    const float* fc1_b   = (const float*)d_in[6];
    const float* fc2_w   = (const float*)d_in[7];
    const float* fc2_b   = (const float*)d_in[8];
    float* out = (float*)d_out;

    char* ws = (char*)d_ws;
    ushort_t* pool1 = (ushort_t*)ws;
    ws += (size_t)B * POS * 32 * sizeof(ushort_t);
    ushort_t* wr = (ushort_t*)ws;
    ws += N_WR * sizeof(ushort_t) + 128;
    ushort_t* wfb = (ushort_t*)ws;
    ws += N_WF * sizeof(ushort_t) + 128;
    ushort_t* pool2cl = (ushort_t*)ws;
    ws += (size_t)B * P2SZ * sizeof(ushort_t) + 128;
    float* Cpart = (float*)ws;
    ws += (size_t)32 * 512 * 128 * sizeof(float) + 128;

    conv1_prep<<<CONV1_BLOCKS + PREP_BLOCKS, 256, 0, stream>>>(
        x, conv1_w, conv1_b, conv2_w, fc1_w, pool1, wr, wfb);
    conv2_mfma<<<B * 3, 256, 0, stream>>>(pool1, wr, conv2_b, pool2cl);
    fc1_mfma<<<512, 256, 0, stream>>>(pool2cl, wfb, Cpart);
    fc1fc2<<<B, 128, 0, stream>>>(Cpart, fc1_b, fc2_w, fc2_b, out);
}

// Round 12
// 130.534 us; speedup vs baseline: 2.0509x; 1.3775x over previous
//
#include <hip/hip_runtime.h>

// LNSNet forward, R11: revert R10's launch_bounds spill disaster (forcing
// (256,6) -> compiler chose VGPR=40 and spilled acc to scratch: WRITE 80MB,
// conv2 72us). conv2 restructured for occupancy instead: 512-thr blocks,
// 8 waves, wave = 3 m-tiles x 2 n-tiles (24 acc VGPRs). Everything else = R7.
// Standing lessons: no device-scope fences (R6/R9); no forced launch_bounds
// near the register budget (R10).

#define B 512
#define POS 676
#define ICP 36
#define P2SZ (64*12*12)
#define SCR 26

typedef unsigned short ushort_t;
typedef ushort_t ushort4v __attribute__((ext_vector_type(4)));
typedef short s16x8 __attribute__((ext_vector_type(8)));
typedef float f32x4 __attribute__((ext_vector_type(4)));
typedef float f32x2 __attribute__((ext_vector_type(2)));

__device__ __forceinline__ ushort_t f2bf(float f) {
    union { float f; unsigned u; } a; a.f = f;
    unsigned r = a.u + 0x7FFFu + ((a.u >> 16) & 1u);
    return (ushort_t)(r >> 16);
}
__device__ __forceinline__ float bf2f(ushort_t u) {
    union { unsigned u; float f; } a; a.u = ((unsigned)u) << 16;
    return a.f;
}

#define N_WR (64 * 9 * 32)
#define N_WF (128 * 9216)
#define CONV1_BLOCKS 3328
#define PREP_BLOCKS  4680

// ---------------- k1: conv1 sliding half-row (packed fp32) + weight prep ----------------
__global__ __launch_bounds__(256) void conv1_prep(const float* __restrict__ x,
                                                  const float* __restrict__ w,
                                                  const float* __restrict__ bias,
                                                  const float* __restrict__ c2w,
                                                  const float* __restrict__ f1w,
                                                  ushort_t* __restrict__ out,
                                                  ushort_t* __restrict__ wr,
                                                  ushort_t* __restrict__ wfb) {
    int blk = blockIdx.x;
    if (blk >= CONV1_BLOCKS) {
        int t = (blk - CONV1_BLOCKS) * 256 + threadIdx.x;
        if (t < N_WR) {
            int ic  = t & 31;
            int tap = (t >> 5) % 9;
            int oc  = t / 288;
            wr[t] = f2bf(c2w[oc * 288 + ic * 9 + tap]);
        } else if (t < N_WR + N_WF) {
            int i  = t - N_WR;
            int oc  = i & 63;
            int pos = (i >> 6) % 144;
            int n   = i / 9216;
            wfb[i] = f2bf(f1w[(size_t)n * 9216 + oc * 144 + pos]);
        }
        return;
    }
    int t = blk * 256 + threadIdx.x;
    int ic = t & 31;
    int r  = t >> 5;
    int h  = r & 1;
    int r2 = r >> 1;
    int py = r2 % 26;
    int b  = r2 / 26;
    int px0 = h * 13;

    const float* wp = w + ic * 9;
    float w00 = wp[0], w01 = wp[1], w02 = wp[2];
    float w10 = wp[3], w11 = wp[4], w12 = wp[5];
    float w20 = wp[6], w21 = wp[7], w22 = wp[8];
    float bv = bias[ic];

    const float* xr = x + b * (54 * 54) + (2 * py) * 54 + 2 * px0;
    ushort_t* po = out + ((size_t)b * POS + py * 26 + px0) * 32 + ic;

    f32x2 p[4], q[4];
#pragma unroll
    for (int rr = 0; rr < 4; ++rr) p[rr] = *reinterpret_cast<const f32x2*>(xr + rr * 54);
#pragma unroll
    for (int rr = 0; rr < 4; ++rr) q[rr] = *reinterpret_cast<const f32x2*>(xr + rr * 54 + 2);

#pragma unroll
    for (int j = 0; j < 13; ++j) {
        f32x2 mid[4];
#pragma unroll
        for (int rr = 0; rr < 4; ++rr) mid[rr] = (f32x2){p[rr].y, q[rr].x};

        f32x2 s0 = p[0] * (f32x2)w00 + mid[0] * (f32x2)w01 + q[0] * (f32x2)w02
                 + p[1] * (f32x2)w10 + mid[1] * (f32x2)w11 + q[1] * (f32x2)w12
                 + p[2] * (f32x2)w20 + mid[2] * (f32x2)w21 + q[2] * (f32x2)w22;
        f32x2 s1 = p[1] * (f32x2)w00 + mid[1] * (f32x2)w01 + q[1] * (f32x2)w02
                 + p[2] * (f32x2)w10 + mid[2] * (f32x2)w11 + q[2] * (f32x2)w12
                 + p[3] * (f32x2)w20 + mid[3] * (f32x2)w21 + q[3] * (f32x2)w22;

        float m = fmaxf(fmaxf(s0.x, s0.y), fmaxf(s1.x, s1.y));
        po[j * 32] = f2bf(fmaxf(m + bv, 0.0f));
        if (j < 12) {
#pragma unroll
            for (int rr = 0; rr < 4; ++rr) {
                p[rr] = q[rr];
                q[rr] = *reinterpret_cast<const f32x2*>(xr + rr * 54 + 2 * j + 4);
            }
        }
    }
}

// ---------------- k2: conv2 MFMA, 512-thr blocks, 8 light waves ----------------
// block = chunk c of image b (pooled rows 4c..4c+3). wave wid: prow = wid>>1,
// nhalf = wid&1 -> 3 m-tiles x 2 n-tiles, 24 acc VGPRs. Scratch aliases image.
__global__ __launch_bounds__(512) void conv2_mfma(const ushort_t* __restrict__ p1,
                                                  const ushort_t* __restrict__ wr,
                                                  const float* __restrict__ bias,
                                                  ushort_t* __restrict__ pool2cl) {
    __shared__ ushort_t lds[260 * ICP];   // 18,720 B
    int blk = blockIdx.x;
    int b = blk / 3, c = blk % 3;
    int tid = threadIdx.x;

    const ushort_t* src = p1 + ((size_t)b * POS + 8 * c * 26) * 32;
    for (int t = tid; t < 260 * 8; t += 512) {
        int pos = t >> 3, off = (t & 7) * 4;
        ushort4v v = *reinterpret_cast<const ushort4v*>(src + pos * 32 + off);
        *reinterpret_cast<ushort4v*>(&lds[pos * ICP + off]) = v;
    }
    __syncthreads();

    int lane = tid & 63, wid = tid >> 6;      // wid 0..7
    int quad = lane >> 4, lr = lane & 15;
    int prow = wid >> 1;                      // pooled row within chunk, 0..3
    int nhalf = wid & 1;                      // oc half: 0 -> oc 0..31, 1 -> 32..63

    int ebase[3];
#pragma unroll
    for (int t = 0; t < 3; ++t) {
        int m  = t * 16 + lr;
        int yl = m / 24;
        int xx = m - yl * 24;
        ebase[t] = ((2 * prow + yl) * 26 + xx) * ICP + quad * 8;
    }

    f32x4 acc[3][2];
#pragma unroll
    for (int t = 0; t < 3; ++t)
#pragma unroll
        for (int n = 0; n < 2; ++n) acc[t][n] = (f32x4){0.f, 0.f, 0.f, 0.f};

    const ushort_t* wb = wr + (size_t)(nhalf * 32 + lr) * 288 + quad * 8;

#pragma unroll
    for (int tap = 0; tap < 9; ++tap) {
        int ky = tap / 3, kx = tap % 3;
        int koff = (ky * 26 + kx) * ICP;
        s16x8 a[3];
#pragma unroll
        for (int t = 0; t < 3; ++t) {
            union { ushort4v s[2]; s16x8 v; } u;
            u.s[0] = *reinterpret_cast<const ushort4v*>(&lds[ebase[t] + koff]);
            u.s[1] = *reinterpret_cast<const ushort4v*>(&lds[ebase[t] + koff + 4]);
            a[t] = u.v;
        }
        s16x8 bf[2];
#pragma unroll
        for (int n = 0; n < 2; ++n)
            bf[n] = *reinterpret_cast<const s16x8*>(wb + (size_t)n * 16 * 288 + tap * 32);
#pragma unroll
        for (int t = 0; t < 3; ++t)
#pragma unroll
            for (int n = 0; n < 2; ++n)
                acc[t][n] = __builtin_amdgcn_mfma_f32_16x16x32_bf16(a[t], bf[n], acc[t][n], 0, 0, 0);
    }
    __syncthreads();   // all waves done with image; alias scratch over it

    // x-pool -> per-wave scratch [oc_local 0..31][i 0..23], stride SCR
    ushort_t* scr = lds + wid * (32 * SCR);   // 8 * 1664 B = 13,312 B < 18,720 B
#pragma unroll
    for (int t = 0; t < 3; ++t)
#pragma unroll
        for (int n = 0; n < 2; ++n) {
            int ocl = n * 16 + lr;
            int i0 = t * 8 + quad * 2;
            float v0 = fmaxf(acc[t][n][0], acc[t][n][1]);
            float v1 = fmaxf(acc[t][n][2], acc[t][n][3]);
            union { ushort_t u2[2]; unsigned w; } pk;
            pk.u2[0] = f2bf(v0); pk.u2[1] = f2bf(v1);
            *reinterpret_cast<unsigned*>(&scr[ocl * SCR + i0]) = pk.w;
        }
    // y-pool: oc_local = lane&31, px-half = lane>>5 (6 px each)
    int ocl = lane & 31;
    int pxh = lane >> 5;
    int oc  = nhalf * 32 + ocl;
    const ushort_t* row = scr + ocl * SCR;
    float bv = bias[oc];
    int py = c * 4 + prow;
    ushort_t* po = pool2cl + ((size_t)b * 144 + py * 12) * 64 + oc;
#pragma unroll
    for (int j = 0; j < 6; ++j) {
        int px = pxh * 6 + j;
        float r0 = bf2f(row[px]);
        float r1 = bf2f(row[px + 12]);
        po[px * 64] = f2bf(fmaxf(fmaxf(r0, r1) + bv, 0.0f));
    }
}

// ---------------- k3: fc1 bf16 MFMA, 32x32-tile waves, permuted K ----------------
__global__ __launch_bounds__(256) void fc1_mfma(const ushort_t* __restrict__ A,
                                                 const ushort_t* __restrict__ W,
                                                 float* __restrict__ Cpart) {
    int tid = threadIdx.x;
    int lane = tid & 63, wid = tid >> 6;
    int lr = lane & 15, quad = lane >> 4;
    int w  = blockIdx.x * 4 + wid;
    int nt = w & 3;
    int ks = (w >> 2) & 31;
    int mt = w >> 7;

    int m0 = mt * 32;
    int n0 = nt * 32;
    int k0 = ks * 288 + quad * 8;
    const ushort_t* a0 = A + (size_t)(m0 + lr) * 9216 + k0;
    const ushort_t* a1 = a0 + (size_t)16 * 9216;
    const ushort_t* b0 = W + (size_t)(n0 + lr) * 9216 + k0;
    const ushort_t* b1 = b0 + (size_t)16 * 9216;

    f32x4 acc[2][2];
#pragma unroll
    for (int i = 0; i < 2; ++i)
#pragma unroll
        for (int j = 0; j < 2; ++j) acc[i][j] = (f32x4){0.f, 0.f, 0.f, 0.f};

#pragma unroll
    for (int kk = 0; kk < 9; ++kk) {
        s16x8 av0 = *reinterpret_cast<const s16x8*>(a0 + kk * 32);
        s16x8 av1 = *reinterpret_cast<const s16x8*>(a1 + kk * 32);
        s16x8 bv0 = *reinterpret_cast<const s16x8*>(b0 + kk * 32);
        s16x8 bv1 = *reinterpret_cast<const s16x8*>(b1 + kk * 32);
        acc[0][0] = __builtin_amdgcn_mfma_f32_16x16x32_bf16(av0, bv0, acc[0][0], 0, 0, 0);
        acc[0][1] = __builtin_amdgcn_mfma_f32_16x16x32_bf16(av0, bv1, acc[0][1], 0, 0, 0);
        acc[1][0] = __builtin_amdgcn_mfma_f32_16x16x32_bf16(av1, bv0, acc[1][0], 0, 0, 0);
        acc[1][1] = __builtin_amdgcn_mfma_f32_16x16x32_bf16(av1, bv1, acc[1][1], 0, 0, 0);
    }

    float* cp = Cpart + (size_t)ks * (512 * 128);
#pragma unroll
    for (int i = 0; i < 2; ++i) {
        int crow = m0 + i * 16 + quad * 4;
#pragma unroll
        for (int j = 0; j < 2; ++j) {
            int col = n0 + j * 16 + lr;
#pragma unroll
            for (int r = 0; r < 4; ++r)
                cp[(size_t)(crow + r) * 128 + col] = acc[i][j][r];
        }
    }
}

// ---------------- k4: fc1 reduce + bias + relu + fc2 ----------------
__global__ __launch_bounds__(128) void fc1fc2(const float* __restrict__ Cpart,
                                              const float* __restrict__ b1,
                                              const float* __restrict__ w2,
                                              const float* __restrict__ b2,
                                              float* __restrict__ out) {
    __shared__ float h[128];
    int b = blockIdx.x, k = threadIdx.x;
    float s = 0.f;
#pragma unroll
    for (int ks = 0; ks < 32; ++ks) s += Cpart[(size_t)ks * (512 * 128) + b * 128 + k];
    h[k] = fmaxf(s + b1[k], 0.0f);
    __syncthreads();
    if (k < 10) {
        const float* wp = w2 + k * 128;
        float acc = 0.f;
#pragma unroll 8
        for (int j = 0; j < 128; ++j) acc += h[j] * wp[j];
        out[b * 10 + k] = acc + b2[k];
    }
}

extern "C" void kernel_launch(void* const* d_in, const int* in_sizes, int n_in,
                              void* d_out, int out_size, void* d_ws, size_t ws_size,
                              hipStream_t stream) {
    const float* x       = (const float*)d_in[0];
    const float* conv1_w = (const float*)d_in[1];
    const float* conv1_b = (const float*)d_in[2];
    const float* conv2_w = (const float*)d_in[3];
    const float* conv2_b = (const float*)d_in[4];
    const float* fc1_w   = (const float*)d_in[5];
    const float* fc1_b   = (const float*)d_in[6];
    const float* fc2_w   = (const float*)d_in[7];
    const float* fc2_b   = (const float*)d_in[8];
    float* out = (float*)d_out;

    char* ws = (char*)d_ws;
    ushort_t* pool1 = (ushort_t*)ws;
    ws += (size_t)B * POS * 32 * sizeof(ushort_t);
    ushort_t* wr = (ushort_t*)ws;
    ws += N_WR * sizeof(ushort_t) + 128;
    ushort_t* wfb = (ushort_t*)ws;
    ws += N_WF * sizeof(ushort_t) + 128;
    ushort_t* pool2cl = (ushort_t*)ws;
    ws += (size_t)B * P2SZ * sizeof(ushort_t) + 128;
    float* Cpart = (float*)ws;
    ws += (size_t)32 * 512 * 128 * sizeof(float) + 128;

    conv1_prep<<<CONV1_BLOCKS + PREP_BLOCKS, 256, 0, stream>>>(
        x, conv1_w, conv1_b, conv2_w, fc1_w, pool1, wr, wfb);
    conv2_mfma<<<B * 3, 512, 0, stream>>>(pool1, wr, conv2_b, pool2cl);
    fc1_mfma<<<512, 256, 0, stream>>>(pool2cl, wfb, Cpart);
    fc1fc2<<<B, 128, 0, stream>>>(Cpart, fc1_b, fc2_w, fc2_b, out);
}